// Round 1
// baseline (454.162 us; speedup 1.0000x reference)
//
#include <hip/hip_runtime.h>
#include <math.h>

#define EPS_ 1e-10f

__device__ __forceinline__ bool better(double v, int i, double w, int j) {
    return (v > w) || (v == w && i < j);
}

// Fused: gate GEMM (fp64 accum) + softmax + top-2 + histogram + rz row sums.
// Grid: N/64 blocks of 256 threads. E fixed at 64.
template<int BM, int BK>
__global__ __launch_bounds__(256)
void router_main(const float* __restrict__ x, const float* __restrict__ W,
                 const float* __restrict__ b, int dim, int N,
                 float* __restrict__ ts, int* __restrict__ sel,
                 int* __restrict__ hist, float* __restrict__ rzrow)
{
    __shared__ float xs[2][BM][BK + 4];   // +4 pad keeps float4 stores aligned, breaks bank conflicts
    __shared__ float wsh[2][BK][64];

    const int tid  = threadIdx.x;
    const int row0 = blockIdx.x * BM;
    const int tcol = tid & 15;   // expert group: experts 4*tcol..4*tcol+3
    const int trow = tid >> 4;   // row group:   rows 4*trow..4*trow+3
    const int ntiles = dim / BK;

    // loader lanes
    const int lrow = tid >> 3;          // 0..31
    const int lk   = (tid & 7) * 4;     // 0..28
    const int lk2  = tid >> 4;          // 0..15
    const int le   = (tid & 15) * 4;    // 0..60

    double acc[4][4];
#pragma unroll
    for (int i = 0; i < 4; i++)
#pragma unroll
        for (int j = 0; j < 4; j++) acc[i][j] = 0.0;

    float4 xr0, xr1, wr0, wr1;
    {
        const float* xp = x + (size_t)(row0 + lrow) * dim + lk;
        xr0 = *(const float4*)xp;
        xr1 = *(const float4*)(xp + (size_t)32 * dim);
        const float* wp = W + (size_t)lk2 * 64 + le;
        wr0 = *(const float4*)wp;
        wr1 = *(const float4*)(wp + 16 * 64);
    }
    *(float4*)&xs[0][lrow][lk]       = xr0;
    *(float4*)&xs[0][lrow + 32][lk]  = xr1;
    *(float4*)&wsh[0][lk2][le]       = wr0;
    *(float4*)&wsh[0][lk2 + 16][le]  = wr1;
    __syncthreads();

    for (int t = 0; t < ntiles; ++t) {
        const int buf = t & 1;
        if (t + 1 < ntiles) {
            const int k0 = (t + 1) * BK;
            const float* xp = x + (size_t)(row0 + lrow) * dim + k0 + lk;
            xr0 = *(const float4*)xp;
            xr1 = *(const float4*)(xp + (size_t)32 * dim);
            const float* wp = W + (size_t)(k0 + lk2) * 64 + le;
            wr0 = *(const float4*)wp;
            wr1 = *(const float4*)(wp + 16 * 64);
        }
#pragma unroll 8
        for (int kk = 0; kk < BK; ++kk) {
            const float a0 = xs[buf][trow * 4 + 0][kk];
            const float a1 = xs[buf][trow * 4 + 1][kk];
            const float a2 = xs[buf][trow * 4 + 2][kk];
            const float a3 = xs[buf][trow * 4 + 3][kk];
            const float4 wv = *(const float4*)&wsh[buf][kk][tcol * 4];
            const double w0 = (double)wv.x, w1 = (double)wv.y,
                         w2 = (double)wv.z, w3 = (double)wv.w;
            acc[0][0] += (double)a0 * w0; acc[0][1] += (double)a0 * w1;
            acc[0][2] += (double)a0 * w2; acc[0][3] += (double)a0 * w3;
            acc[1][0] += (double)a1 * w0; acc[1][1] += (double)a1 * w1;
            acc[1][2] += (double)a1 * w2; acc[1][3] += (double)a1 * w3;
            acc[2][0] += (double)a2 * w0; acc[2][1] += (double)a2 * w1;
            acc[2][2] += (double)a2 * w2; acc[2][3] += (double)a2 * w3;
            acc[3][0] += (double)a3 * w0; acc[3][1] += (double)a3 * w1;
            acc[3][2] += (double)a3 * w2; acc[3][3] += (double)a3 * w3;
        }
        __syncthreads();
        if (t + 1 < ntiles) {
            const int nb = (t + 1) & 1;
            *(float4*)&xs[nb][lrow][lk]      = xr0;
            *(float4*)&xs[nb][lrow + 32][lk] = xr1;
            *(float4*)&wsh[nb][lk2][le]      = wr0;
            *(float4*)&wsh[nb][lk2 + 16][le] = wr1;
            __syncthreads();
        }
    }

    // epilogue: per-row softmax / top-2 / rz
    const float4 bb = *(const float4*)(b + tcol * 4);
#pragma unroll
    for (int i = 0; i < 4; ++i) {
        const int grow = row0 + trow * 4 + i;
        double z[4];
        z[0] = acc[i][0] + (double)bb.x;
        z[1] = acc[i][1] + (double)bb.y;
        z[2] = acc[i][2] + (double)bb.z;
        z[3] = acc[i][3] + (double)bb.w;

        // local top2 (ascending index => ties keep lower index)
        double v1 = -1e300, v2 = -1e300;
        int i1 = 0x7fffffff, i2 = 0x7fffffff;
#pragma unroll
        for (int j = 0; j < 4; ++j) {
            const double v = z[j];
            const int e = tcol * 4 + j;
            if (v > v1) { v2 = v1; i2 = i1; v1 = v; i1 = e; }
            else if (v > v2) { v2 = v; i2 = e; }
        }
        // butterfly merge across the 16 lanes sharing this row
#pragma unroll
        for (int m = 1; m < 16; m <<= 1) {
            const double w1 = __shfl_xor(v1, m, 16); const int j1 = __shfl_xor(i1, m, 16);
            const double w2 = __shfl_xor(v2, m, 16); const int j2 = __shfl_xor(i2, m, 16);
            if (better(w1, j1, v1, i1)) {
                double nv2; int ni2;
                if (better(v1, i1, w2, j2)) { nv2 = v1; ni2 = i1; }
                else                        { nv2 = w2; ni2 = j2; }
                v1 = w1; i1 = j1; v2 = nv2; i2 = ni2;
            } else if (better(w1, j1, v2, i2)) { v2 = w1; i2 = j1; }
        }

        // softmax (max = v1)
        float sloc[4];
        float ssum = 0.0f;
#pragma unroll
        for (int j = 0; j < 4; ++j) { sloc[j] = expf((float)(z[j] - v1)); ssum += sloc[j]; }
#pragma unroll
        for (int m = 1; m < 16; m <<= 1) ssum += __shfl_xor(ssum, m, 16);
        const float inv = 1.0f / ssum;

        float srz = 0.0f;
#pragma unroll
        for (int j = 0; j < 4; ++j) {
            float sc = sloc[j] * inv;
            sc = fminf(fmaxf(sc, EPS_), 1.0f - EPS_);
            srz += sc / (1.0f - sc);
        }
#pragma unroll
        for (int m = 1; m < 16; m <<= 1) srz += __shfl_xor(srz, m, 16);

        if (tcol == 0) {
            float s1 = fminf(fmaxf(inv, EPS_), 1.0f - EPS_);                  // exp(0)/sum
            float s2 = fminf(fmaxf(expf((float)(v2 - v1)) * inv, EPS_), 1.0f - EPS_);
            ts[grow * 2 + 0] = s1;
            ts[grow * 2 + 1] = s2;
            sel[grow * 2 + 0] = i1;
            sel[grow * 2 + 1] = i2;
            atomicAdd(&hist[i1], 1);
            atomicAdd(&hist[i2], 1);
            rzrow[grow] = srz;
        }
    }
}

// per-batch logsumexp reduce; batch_size/seq_len read from device scalars
__global__ void rz_reduce(const float* __restrict__ rzrow,
                          const int* __restrict__ bs_p, const int* __restrict__ sl_p,
                          float* __restrict__ out_rz)
{
    __shared__ float red[256];
    const int tid = threadIdx.x;
    const int nb = bs_p[0];
    const int seq = sl_p[0];
    double accum = 0.0;
    for (int bb = 0; bb < nb; ++bb) {
        float s = 0.0f;
        for (int i = tid; i < seq; i += 256) s += rzrow[(size_t)bb * seq + i];
        red[tid] = s; __syncthreads();
        for (int st = 128; st > 0; st >>= 1) {
            if (tid < st) red[tid] += red[tid + st];
            __syncthreads();
        }
        if (tid == 0) accum += log((double)red[0]);
        __syncthreads();
    }
    if (tid == 0) out_rz[0] = (float)(accum / nb);
}

// stable counting sort by expert: one wave per expert
__global__ void sort_slots(const int* __restrict__ sel, const float* __restrict__ ts,
                           const int* __restrict__ hist, int total,
                           float* __restrict__ out_sc, float* __restrict__ out_idx,
                           float* __restrict__ out_cnt)
{
    const int e = blockIdx.x;
    const int lane = threadIdx.x;   // 64 threads
    const int c = hist[lane];
    if (lane == e) out_cnt[e] = (float)c;
    int incl = c;
#pragma unroll
    for (int m = 1; m < 64; m <<= 1) {
        const int w = __shfl_up(incl, m, 64);
        if (lane >= m) incl += w;
    }
    int start = __shfl(incl, e, 64) - __shfl(c, e, 64);
    for (int base = 0; base < total; base += 64) {
        const int idx = base + lane;
        const int ex = sel[idx];
        const bool mt = (ex == e);
        const unsigned long long mask = __ballot(mt);
        const int pre = __popcll(mask & ((1ull << lane) - 1ull));
        if (mt) {
            out_sc[start + pre]  = ts[idx];
            out_idx[start + pre] = (float)(idx >> 1);
        }
        start += __popcll(mask);
    }
}

extern "C" void kernel_launch(void* const* d_in, const int* in_sizes, int n_in,
                              void* d_out, int out_size, void* d_ws, size_t ws_size,
                              hipStream_t stream)
{
    const float* x = (const float*)d_in[0];
    const float* W = (const float*)d_in[1];
    const float* b = (const float*)d_in[2];
    const int* bs_p = (const int*)d_in[3];
    const int* sl_p = (const int*)d_in[4];

    const int E  = in_sizes[2];            // 64
    const int dim = in_sizes[1] / E;       // 2048
    const int N   = in_sizes[0] / dim;     // 16384
    const int total = N * 2;               // slots

    char* ws = (char*)d_ws;
    float* ts   = (float*)ws;                                // total floats
    int*   sel  = (int*)(ws + (size_t)total * 4);            // total ints
    int*   hist = (int*)(ws + (size_t)total * 8);            // E ints
    float* rzrow = (float*)(ws + (size_t)total * 8 + 256);   // N floats

    float* out_sc  = (float*)d_out;
    float* out_idx = out_sc + total;
    float* out_cnt = out_idx + total;
    float* out_rz  = out_cnt + E;

    hipMemsetAsync(hist, 0, E * sizeof(int), stream);

    hipLaunchKernelGGL((router_main<64, 32>), dim3(N / 64), dim3(256), 0, stream,
                       x, W, b, dim, N, ts, sel, hist, rzrow);
    hipLaunchKernelGGL(rz_reduce, dim3(1), dim3(256), 0, stream,
                       rzrow, bs_p, sl_p, out_rz);
    hipLaunchKernelGGL(sort_slots, dim3(E), dim3(64), 0, stream,
                       sel, ts, hist, total, out_sc, out_idx, out_cnt);
}

// Round 2
// 381.326 us; speedup vs baseline: 1.1910x; 1.1910x over previous
//
#include <hip/hip_runtime.h>
#include <math.h>

#define EPS_ 1e-10f
#define MARGIN 2e-3f

__device__ __forceinline__ bool betterf(float v, int i, float w, int j) {
    return (v > w) || (v == w && i < j);
}
__device__ __forceinline__ bool betterd(double v, int i, double w, int j) {
    return (v > w) || (v == w && i < j);
}

// Fused fp32 gate GEMM + softmax + top-2 (+third-max gap flagging) + rz batch sums.
// Grid: N/BM blocks of 256 threads. E fixed at 64.
template<int BM, int BK>
__global__ __launch_bounds__(256)
void router_main(const float* __restrict__ x, const float* __restrict__ W,
                 const float* __restrict__ b, int dim,
                 const int* __restrict__ sl_p,
                 float* __restrict__ ts, int* __restrict__ sel,
                 double* __restrict__ bsum,
                 int* __restrict__ nflags, int* __restrict__ flaglist)
{
    __shared__ float xs[2][BK][BM + 4];   // transposed: xs[kk][row]; stride 68 keeps 16B align
    __shared__ float wsh[2][BK][64];
    __shared__ float rsum[16];

    const int tid  = threadIdx.x;
    const int row0 = blockIdx.x * BM;
    const int tcol = tid & 15;   // expert group: experts 4*tcol..+3
    const int trow = tid >> 4;   // row group:   rows 4*trow..+3
    const int ntiles = dim / BK;

    // loader lanes
    const int xrow = tid >> 3;          // 0..31 (x rows; +32 for second load)
    const int xk4  = (tid & 7) * 4;     // 0..28
    const int wk   = tid >> 4;          // 0..15 (W k-rows; +16 for second)
    const int we4  = (tid & 15) * 4;    // 0..60

    float acc[4][4] = {};

    const float* xbase = x + (size_t)(row0 + xrow) * dim + xk4;

    float4 xr0, xr1, wr0, wr1;
    {
        xr0 = *(const float4*)xbase;
        xr1 = *(const float4*)(xbase + (size_t)32 * dim);
        const float* wp = W + (size_t)wk * 64 + we4;
        wr0 = *(const float4*)wp;
        wr1 = *(const float4*)(wp + 16 * 64);
    }
    xs[0][xk4 + 0][xrow] = xr0.x; xs[0][xk4 + 1][xrow] = xr0.y;
    xs[0][xk4 + 2][xrow] = xr0.z; xs[0][xk4 + 3][xrow] = xr0.w;
    xs[0][xk4 + 0][xrow + 32] = xr1.x; xs[0][xk4 + 1][xrow + 32] = xr1.y;
    xs[0][xk4 + 2][xrow + 32] = xr1.z; xs[0][xk4 + 3][xrow + 32] = xr1.w;
    *(float4*)&wsh[0][wk][we4]      = wr0;
    *(float4*)&wsh[0][wk + 16][we4] = wr1;
    __syncthreads();

    for (int t = 0; t < ntiles; ++t) {
        const int buf = t & 1;
        if (t + 1 < ntiles) {
            const int k0 = (t + 1) * BK;
            xr0 = *(const float4*)(xbase + k0);
            xr1 = *(const float4*)(xbase + k0 + (size_t)32 * dim);
            const float* wp = W + (size_t)(k0 + wk) * 64 + we4;
            wr0 = *(const float4*)wp;
            wr1 = *(const float4*)(wp + 16 * 64);
        }
        {
            const float (*__restrict__ xsb)[BM + 4] = xs[buf];
            const float (*__restrict__ wsb)[64]     = wsh[buf];
#pragma unroll
            for (int kk = 0; kk < BK; ++kk) {
                const float4 xv = *(const float4*)&xsb[kk][trow * 4];
                const float4 wv = *(const float4*)&wsb[kk][tcol * 4];
                acc[0][0] += xv.x * wv.x; acc[0][1] += xv.x * wv.y;
                acc[0][2] += xv.x * wv.z; acc[0][3] += xv.x * wv.w;
                acc[1][0] += xv.y * wv.x; acc[1][1] += xv.y * wv.y;
                acc[1][2] += xv.y * wv.z; acc[1][3] += xv.y * wv.w;
                acc[2][0] += xv.z * wv.x; acc[2][1] += xv.z * wv.y;
                acc[2][2] += xv.z * wv.z; acc[2][3] += xv.z * wv.w;
                acc[3][0] += xv.w * wv.x; acc[3][1] += xv.w * wv.y;
                acc[3][2] += xv.w * wv.z; acc[3][3] += xv.w * wv.w;
            }
        }
        __syncthreads();
        if (t + 1 < ntiles) {
            const int nb2 = (t + 1) & 1;
            xs[nb2][xk4 + 0][xrow] = xr0.x; xs[nb2][xk4 + 1][xrow] = xr0.y;
            xs[nb2][xk4 + 2][xrow] = xr0.z; xs[nb2][xk4 + 3][xrow] = xr0.w;
            xs[nb2][xk4 + 0][xrow + 32] = xr1.x; xs[nb2][xk4 + 1][xrow + 32] = xr1.y;
            xs[nb2][xk4 + 2][xrow + 32] = xr1.z; xs[nb2][xk4 + 3][xrow + 32] = xr1.w;
            *(float4*)&wsh[nb2][wk][we4]      = wr0;
            *(float4*)&wsh[nb2][wk + 16][we4] = wr1;
            __syncthreads();
        }
    }

    // epilogue: per-row softmax / top-2 / gap flag / rz
    const float4 bb = *(const float4*)(b + tcol * 4);
    const int seq = sl_p[0];
    const int batch = row0 / seq;
    float rz4 = 0.0f;

#pragma unroll
    for (int i = 0; i < 4; ++i) {
        const int grow = row0 + trow * 4 + i;
        float z[4];
        z[0] = acc[i][0] + bb.x; z[1] = acc[i][1] + bb.y;
        z[2] = acc[i][2] + bb.z; z[3] = acc[i][3] + bb.w;

        float v1 = -3.4e38f, v2 = -3.4e38f;
        int i1 = 1 << 30, i2 = 1 << 30;
#pragma unroll
        for (int j = 0; j < 4; ++j) {
            const float v = z[j];
            const int e = tcol * 4 + j;
            if (v > v1) { v2 = v1; i2 = i1; v1 = v; i1 = e; }
            else if (v > v2) { v2 = v; i2 = e; }
        }
#pragma unroll
        for (int m = 1; m < 16; m <<= 1) {
            const float w1 = __shfl_xor(v1, m, 16); const int j1 = __shfl_xor(i1, m, 16);
            const float w2 = __shfl_xor(v2, m, 16); const int j2 = __shfl_xor(i2, m, 16);
            if (betterf(w1, j1, v1, i1)) {
                float nv2; int ni2;
                if (betterf(v1, i1, w2, j2)) { nv2 = v1; ni2 = i1; }
                else                         { nv2 = w2; ni2 = j2; }
                v1 = w1; i1 = j1; v2 = nv2; i2 = ni2;
            } else if (betterf(w1, j1, v2, i2)) { v2 = w1; i2 = j1; }
        }

        // third-highest value (for the rank-2/3 gap check)
        float v3 = -3.4e38f;
#pragma unroll
        for (int j = 0; j < 4; ++j) {
            const int e = tcol * 4 + j;
            if (e != i1 && e != i2) v3 = fmaxf(v3, z[j]);
        }
#pragma unroll
        for (int m = 1; m < 16; m <<= 1) v3 = fmaxf(v3, __shfl_xor(v3, m, 16));

        // softmax (max = v1)
        float sloc[4];
        float ssum = 0.0f;
#pragma unroll
        for (int j = 0; j < 4; ++j) { sloc[j] = expf(z[j] - v1); ssum += sloc[j]; }
#pragma unroll
        for (int m = 1; m < 16; m <<= 1) ssum += __shfl_xor(ssum, m, 16);
        const float inv = 1.0f / ssum;

        float srz = 0.0f;
#pragma unroll
        for (int j = 0; j < 4; ++j) {
            float sc = sloc[j] * inv;
            sc = fminf(fmaxf(sc, EPS_), 1.0f - EPS_);
            srz += sc / (1.0f - sc);
        }
#pragma unroll
        for (int m = 1; m < 16; m <<= 1) srz += __shfl_xor(srz, m, 16);
        rz4 += srz;

        if (tcol == 0) {
            const float s1 = fminf(fmaxf(inv, EPS_), 1.0f - EPS_);
            const float s2 = fminf(fmaxf(expf(v2 - v1) * inv, EPS_), 1.0f - EPS_);
            ts[grow * 2 + 0] = s1;
            ts[grow * 2 + 1] = s2;
            sel[grow * 2 + 0] = i1;
            sel[grow * 2 + 1] = i2;
            if ((v1 - v2) < MARGIN || (v2 - v3) < MARGIN) {
                const int slot = atomicAdd(nflags, 1);
                flaglist[slot] = grow;
            }
        }
    }

    if (tcol == 0) rsum[trow] = rz4;
    __syncthreads();
    if (tid == 0) {
        float tot = 0.0f;
#pragma unroll
        for (int r = 0; r < 16; ++r) tot += rsum[r];
        atomicAdd(&bsum[batch], (double)tot);
    }
}

// fp64 recompute of flagged near-tie rows; overwrites ts/sel for those rows.
__global__ __launch_bounds__(256)
void fixup(const float* __restrict__ x, const float* __restrict__ W,
           const float* __restrict__ b, int dim,
           const int* __restrict__ nflags, const int* __restrict__ flaglist,
           float* __restrict__ ts, int* __restrict__ sel)
{
    __shared__ double red[256];
    const int tid = threadIdx.x;
    const int e = tid & 63;
    const int q = tid >> 6;
    const int nf = *nflags;
    const int quarter = dim >> 2;

    for (int f = blockIdx.x; f < nf; f += gridDim.x) {
        const int row = flaglist[f];
        const float* xr = x + (size_t)row * dim;
        double s = 0.0;
        const int k0 = q * quarter;
        for (int k = k0; k < k0 + quarter; ++k)
            s = fma((double)xr[k], (double)W[(size_t)k * 64 + e], s);
        red[tid] = s;
        __syncthreads();
        if (tid < 128) red[tid] += red[tid + 128];
        __syncthreads();
        if (tid < 64) {
            const double z = red[tid] + red[tid + 64] + (double)b[e];
            double v1 = z, v2 = -1e300;
            int i1 = e, i2 = 1 << 30;
#pragma unroll
            for (int m = 1; m < 64; m <<= 1) {
                const double w1 = __shfl_xor(v1, m, 64); const int j1 = __shfl_xor(i1, m, 64);
                const double w2 = __shfl_xor(v2, m, 64); const int j2 = __shfl_xor(i2, m, 64);
                if (betterd(w1, j1, v1, i1)) {
                    double nv2; int ni2;
                    if (betterd(v1, i1, w2, j2)) { nv2 = v1; ni2 = i1; }
                    else                         { nv2 = w2; ni2 = j2; }
                    v1 = w1; i1 = j1; v2 = nv2; i2 = ni2;
                } else if (betterd(w1, j1, v2, i2)) { v2 = w1; i2 = j1; }
            }
            float sl = expf((float)(z - v1));
            float ssum = sl;
#pragma unroll
            for (int m = 1; m < 64; m <<= 1) ssum += __shfl_xor(ssum, m, 64);
            const float inv = 1.0f / ssum;
            if (e == 0) {
                const float s1 = fminf(fmaxf(inv, EPS_), 1.0f - EPS_);
                const float s2 = fminf(fmaxf(expf((float)(v2 - v1)) * inv, EPS_), 1.0f - EPS_);
                ts[row * 2 + 0] = s1;
                ts[row * 2 + 1] = s2;
                sel[row * 2 + 0] = i1;
                sel[row * 2 + 1] = i2;
            }
        }
        __syncthreads();
    }
}

// per-64-slot-chunk expert counts + global histogram
__global__ void hist_chunks(const int* __restrict__ sel, int* __restrict__ hist,
                            int* __restrict__ cnt2)
{
    __shared__ int cnt[64];
    const int lane = threadIdx.x;   // 64
    const int c = blockIdx.x;
    cnt[lane] = 0;
    __syncthreads();
    const int ex = sel[c * 64 + lane];
    atomicAdd(&cnt[ex], 1);
    __syncthreads();
    cnt2[c * 64 + lane] = cnt[lane];
    if (cnt[lane]) atomicAdd(&hist[lane], cnt[lane]);
}

// expert offsets + per-chunk bases + out_cnt + rz finalize
__global__ void combine(const int* __restrict__ hist, const int* __restrict__ cnt2,
                        int nchunks, int* __restrict__ cbase,
                        const double* __restrict__ bsum,
                        const int* __restrict__ bs_p,
                        float* __restrict__ out_cnt, float* __restrict__ out_rz)
{
    const int e = threadIdx.x;   // 64
    const int c0 = hist[e];
    int incl = c0;
#pragma unroll
    for (int m = 1; m < 64; m <<= 1) {
        const int w = __shfl_up(incl, m, 64);
        if (e >= m) incl += w;
    }
    int run = incl - c0;         // exclusive scan = expert start
    out_cnt[e] = (float)c0;
    for (int c = 0; c < nchunks; ++c) {
        cbase[c * 64 + e] = run;
        run += cnt2[c * 64 + e];
    }
    if (e == 0) {
        const int nb = bs_p[0];
        double a = 0.0;
        for (int i = 0; i < nb; ++i) a += log(bsum[i]);
        out_rz[0] = (float)(a / nb);
    }
}

// stable scatter: one ballot-free LDS-prefix per 64-slot chunk
__global__ void scatter(const int* __restrict__ sel, const float* __restrict__ ts,
                        const int* __restrict__ cbase,
                        float* __restrict__ out_sc, float* __restrict__ out_idx)
{
    __shared__ int shx[64];
    const int lane = threadIdx.x;   // 64
    const int c = blockIdx.x;
    const int idx = c * 64 + lane;
    const int ex = sel[idx];
    shx[lane] = ex;
    __syncthreads();
    int pre = 0;
#pragma unroll
    for (int j = 0; j < 64; ++j) pre += (int)((j < lane) && (shx[j] == ex));
    const int pos = cbase[c * 64 + ex] + pre;
    out_sc[pos]  = ts[idx];
    out_idx[pos] = (float)(idx >> 1);
}

extern "C" void kernel_launch(void* const* d_in, const int* in_sizes, int n_in,
                              void* d_out, int out_size, void* d_ws, size_t ws_size,
                              hipStream_t stream)
{
    const float* x = (const float*)d_in[0];
    const float* W = (const float*)d_in[1];
    const float* b = (const float*)d_in[2];
    const int* bs_p = (const int*)d_in[3];
    const int* sl_p = (const int*)d_in[4];

    const int E   = in_sizes[2];           // 64
    const int dim = in_sizes[1] / E;       // 2048
    const int N   = in_sizes[0] / dim;     // 16384
    const int total = N * 2;               // slots
    const int nchunks = total / 64;        // 512

    char* ws = (char*)d_ws;
    int*    hist     = (int*)ws;                                   // 64 ints
    double* bsum     = (double*)(ws + 256);                        // <=64 doubles
    int*    nflags   = (int*)(ws + 768);                           // 1 int
    float*  ts       = (float*)(ws + 1024);                        // total floats
    int*    sel      = (int*)(ws + 1024 + (size_t)total * 4);      // total ints
    int*    flaglist = (int*)(ws + 1024 + (size_t)total * 8);      // N ints
    int*    cnt2     = (int*)(ws + 1024 + (size_t)total * 8 + (size_t)N * 4);
    int*    cbase    = cnt2 + (size_t)nchunks * 64;

    float* out_sc  = (float*)d_out;
    float* out_idx = out_sc + total;
    float* out_cnt = out_idx + total;
    float* out_rz  = out_cnt + E;

    hipMemsetAsync(ws, 0, 1024, stream);

    hipLaunchKernelGGL((router_main<64, 32>), dim3(N / 64), dim3(256), 0, stream,
                       x, W, b, dim, sl_p, ts, sel, bsum, nflags, flaglist);
    hipLaunchKernelGGL(fixup, dim3(256), dim3(256), 0, stream,
                       x, W, b, dim, nflags, flaglist, ts, sel);
    hipLaunchKernelGGL(hist_chunks, dim3(nchunks), dim3(64), 0, stream,
                       sel, hist, cnt2);
    hipLaunchKernelGGL(combine, dim3(1), dim3(64), 0, stream,
                       hist, cnt2, nchunks, cbase, bsum, bs_p, out_cnt, out_rz);
    hipLaunchKernelGGL(scatter, dim3(nchunks), dim3(64), 0, stream,
                       sel, ts, cbase, out_sc, out_idx);
}

// Round 3
// 370.957 us; speedup vs baseline: 1.2243x; 1.0280x over previous
//
#include <hip/hip_runtime.h>
#include <math.h>

#define EPS_ 1e-10f
#define MARGIN 2e-3f

__device__ __forceinline__ bool betterf(float v, int i, float w, int j) {
    return (v > w) || (v == w && i < j);
}
__device__ __forceinline__ bool betterd(double v, int i, double w, int j) {
    return (v > w) || (v == w && i < j);
}

// ---------------------------------------------------------------------------
// K-split GEMM, zero LDS. Thread = 8 rows x 4 experts; wave = 32 rows x 64 e.
// Block = 256 thr -> 128 rows, all 64 experts, one K-slice of dim/ksplit.
// zpart[ks][row][e] = sum over slice of x[row][k]*W[k][e]   (no bias)
// ---------------------------------------------------------------------------
__global__ __launch_bounds__(256, 4)
void gemm_kslice(const float* __restrict__ x, const float* __restrict__ W,
                 int dim, int N, int ksplit, int nrb,
                 float* __restrict__ zpart)
{
    const int rb = blockIdx.x % nrb;
    const int ks = blockIdx.x / nrb;
    const int kslice = dim / ksplit;
    const int k0 = ks * kslice;

    const int e4   = (threadIdx.x & 15) * 4;
    const int rt   = threadIdx.x >> 4;          // 0..15
    const int row0 = rb * 128 + rt * 8;

    float acc[8][4] = {};

    const float* xp[8];
#pragma unroll
    for (int r = 0; r < 8; ++r)
        xp[r] = x + (size_t)(row0 + r) * dim + k0;
    const float* wp = W + (size_t)k0 * 64 + e4;

    for (int kk = 0; kk < kslice; kk += 4) {
        float4 xv[8];
#pragma unroll
        for (int r = 0; r < 8; ++r)
            xv[r] = *(const float4*)(xp[r] + kk);

#define STEP_(J, C)                                                        \
        {                                                                  \
            const float4 wv = *(const float4*)(wp + (size_t)(kk + J) * 64);\
            _Pragma("unroll")                                              \
            for (int r = 0; r < 8; ++r) {                                  \
                acc[r][0] += xv[r].C * wv.x;                               \
                acc[r][1] += xv[r].C * wv.y;                               \
                acc[r][2] += xv[r].C * wv.z;                               \
                acc[r][3] += xv[r].C * wv.w;                               \
            }                                                              \
        }
        STEP_(0, x) STEP_(1, y) STEP_(2, z) STEP_(3, w)
#undef STEP_
    }

#pragma unroll
    for (int r = 0; r < 8; ++r) {
        float4 o;
        o.x = acc[r][0]; o.y = acc[r][1]; o.z = acc[r][2]; o.w = acc[r][3];
        *(float4*)&zpart[((size_t)ks * N + row0 + r) * 64 + e4] = o;
    }
}

// ---------------------------------------------------------------------------
// Epilogue: one wave per row. Sum K-split partials (fixed order), + bias,
// top-2 w/ tie-break, 3rd-max gap flag, softmax, rz row sum.
// ---------------------------------------------------------------------------
__global__ __launch_bounds__(256)
void epilogue(const float* __restrict__ zpart, const float* __restrict__ b,
              int N, int ksplit,
              float* __restrict__ ts, int* __restrict__ sel,
              float* __restrict__ rzrow,
              int* __restrict__ nflags, int* __restrict__ flaglist)
{
    const int lane = threadIdx.x & 63;
    const int row  = blockIdx.x * 4 + (threadIdx.x >> 6);
    if (row >= N) return;

    float z = b[lane];
    for (int ks = 0; ks < ksplit; ++ks)
        z += zpart[((size_t)ks * N + row) * 64 + lane];

    // 64-lane top-2 butterfly (ties -> lower index)
    float v1 = z, v2 = -3.4e38f;
    int i1 = lane, i2 = 1 << 30;
#pragma unroll
    for (int m = 1; m < 64; m <<= 1) {
        const float w1 = __shfl_xor(v1, m, 64); const int j1 = __shfl_xor(i1, m, 64);
        const float w2 = __shfl_xor(v2, m, 64); const int j2 = __shfl_xor(i2, m, 64);
        if (betterf(w1, j1, v1, i1)) {
            float nv2; int ni2;
            if (betterf(v1, i1, w2, j2)) { nv2 = v1; ni2 = i1; }
            else                         { nv2 = w2; ni2 = j2; }
            v1 = w1; i1 = j1; v2 = nv2; i2 = ni2;
        } else if (betterf(w1, j1, v2, i2)) { v2 = w1; i2 = j1; }
    }

    // third-highest
    float m3 = (lane == i1 || lane == i2) ? -3.4e38f : z;
#pragma unroll
    for (int m = 1; m < 64; m <<= 1) m3 = fmaxf(m3, __shfl_xor(m3, m, 64));

    // softmax + rz
    const float ex = expf(z - v1);
    float ssum = ex;
#pragma unroll
    for (int m = 1; m < 64; m <<= 1) ssum += __shfl_xor(ssum, m, 64);
    const float inv = 1.0f / ssum;

    float sc = fminf(fmaxf(ex * inv, EPS_), 1.0f - EPS_);
    float srz = sc / (1.0f - sc);
#pragma unroll
    for (int m = 1; m < 64; m <<= 1) srz += __shfl_xor(srz, m, 64);

    if (lane == 0) {
        const float s1 = fminf(fmaxf(inv, EPS_), 1.0f - EPS_);
        const float s2 = fminf(fmaxf(expf(v2 - v1) * inv, EPS_), 1.0f - EPS_);
        ts[row * 2 + 0] = s1;
        ts[row * 2 + 1] = s2;
        sel[row * 2 + 0] = i1;
        sel[row * 2 + 1] = i2;
        rzrow[row] = srz;
        if ((v1 - v2) < MARGIN || (v2 - m3) < MARGIN) {
            const int slot = atomicAdd(nflags, 1);
            flaglist[slot] = row;
        }
    }
}

// ---------------------------------------------------------------------------
// fp64 recompute of flagged near-tie rows (4 independent accumulator chains).
// ---------------------------------------------------------------------------
__global__ __launch_bounds__(256)
void fixup(const float* __restrict__ x, const float* __restrict__ W,
           const float* __restrict__ b, int dim,
           const int* __restrict__ nflags, const int* __restrict__ flaglist,
           float* __restrict__ ts, int* __restrict__ sel)
{
    __shared__ double red[256];
    const int tid = threadIdx.x;
    const int e = tid & 63;
    const int q = tid >> 6;
    const int nf = *nflags;
    const int quarter = dim >> 2;

    for (int f = blockIdx.x; f < nf; f += gridDim.x) {
        const int row = flaglist[f];
        const float* xr = x + (size_t)row * dim;
        const int k0 = q * quarter;
        double a0 = 0.0, a1 = 0.0, a2 = 0.0, a3 = 0.0;
        for (int k = k0; k < k0 + quarter; k += 4) {
            a0 = fma((double)xr[k + 0], (double)W[(size_t)(k + 0) * 64 + e], a0);
            a1 = fma((double)xr[k + 1], (double)W[(size_t)(k + 1) * 64 + e], a1);
            a2 = fma((double)xr[k + 2], (double)W[(size_t)(k + 2) * 64 + e], a2);
            a3 = fma((double)xr[k + 3], (double)W[(size_t)(k + 3) * 64 + e], a3);
        }
        red[tid] = (a0 + a1) + (a2 + a3);
        __syncthreads();
        if (tid < 128) red[tid] += red[tid + 128];
        __syncthreads();
        if (tid < 64) {
            const double z = red[tid] + red[tid + 64] + (double)b[e];
            double v1 = z, v2 = -1e300;
            int i1 = e, i2 = 1 << 30;
#pragma unroll
            for (int m = 1; m < 64; m <<= 1) {
                const double w1 = __shfl_xor(v1, m, 64); const int j1 = __shfl_xor(i1, m, 64);
                const double w2 = __shfl_xor(v2, m, 64); const int j2 = __shfl_xor(i2, m, 64);
                if (betterd(w1, j1, v1, i1)) {
                    double nv2; int ni2;
                    if (betterd(v1, i1, w2, j2)) { nv2 = v1; ni2 = i1; }
                    else                         { nv2 = w2; ni2 = j2; }
                    v1 = w1; i1 = j1; v2 = nv2; i2 = ni2;
                } else if (betterd(w1, j1, v2, i2)) { v2 = w1; i2 = j1; }
            }
            float sl = expf((float)(z - v1));
            float ssum = sl;
#pragma unroll
            for (int m = 1; m < 64; m <<= 1) ssum += __shfl_xor(ssum, m, 64);
            const float inv = 1.0f / ssum;
            if (e == 0) {
                const float s1 = fminf(fmaxf(inv, EPS_), 1.0f - EPS_);
                const float s2 = fminf(fmaxf(expf((float)(v2 - v1)) * inv, EPS_), 1.0f - EPS_);
                ts[row * 2 + 0] = s1;
                ts[row * 2 + 1] = s2;
                sel[row * 2 + 0] = i1;
                sel[row * 2 + 1] = i2;
            }
        }
        __syncthreads();
    }
}

// per-64-slot-chunk expert counts + global histogram
__global__ void hist_chunks(const int* __restrict__ sel, int* __restrict__ hist,
                            int* __restrict__ cnt2)
{
    __shared__ int cnt[64];
    const int lane = threadIdx.x;   // 64
    const int c = blockIdx.x;
    cnt[lane] = 0;
    __syncthreads();
    const int ex = sel[c * 64 + lane];
    atomicAdd(&cnt[ex], 1);
    __syncthreads();
    cnt2[c * 64 + lane] = cnt[lane];
    if (cnt[lane]) atomicAdd(&hist[lane], cnt[lane]);
}

// per-batch rz sums (deterministic tree)
__global__ void rz_batch(const float* __restrict__ rzrow,
                         const int* __restrict__ bs_p, const int* __restrict__ sl_p,
                         double* __restrict__ bsum)
{
    __shared__ double red[256];
    const int nb = bs_p[0];
    const int seq = sl_p[0];
    for (int bb = blockIdx.x; bb < nb; bb += gridDim.x) {
        double s = 0.0;
        for (int i = threadIdx.x; i < seq; i += 256)
            s += (double)rzrow[(size_t)bb * seq + i];
        red[threadIdx.x] = s;
        __syncthreads();
        for (int st = 128; st > 0; st >>= 1) {
            if (threadIdx.x < st) red[threadIdx.x] += red[threadIdx.x + st];
            __syncthreads();
        }
        if (threadIdx.x == 0) bsum[bb] = red[0];
        __syncthreads();
    }
}

// expert offsets + per-chunk bases + out_cnt + rz finalize
__global__ void combine(const int* __restrict__ hist, const int* __restrict__ cnt2,
                        int nchunks, int* __restrict__ cbase,
                        const double* __restrict__ bsum,
                        const int* __restrict__ bs_p,
                        float* __restrict__ out_cnt, float* __restrict__ out_rz)
{
    const int e = threadIdx.x;   // 64
    const int c0 = hist[e];
    int incl = c0;
#pragma unroll
    for (int m = 1; m < 64; m <<= 1) {
        const int w = __shfl_up(incl, m, 64);
        if (e >= m) incl += w;
    }
    int run = incl - c0;         // exclusive scan = expert start
    out_cnt[e] = (float)c0;
    for (int c = 0; c < nchunks; ++c) {
        cbase[c * 64 + e] = run;
        run += cnt2[c * 64 + e];
    }
    if (e == 0) {
        const int nb = bs_p[0];
        double a = 0.0;
        for (int i = 0; i < nb; ++i) a += log(bsum[i]);
        out_rz[0] = (float)(a / nb);
    }
}

// stable scatter per 64-slot chunk
__global__ void scatter(const int* __restrict__ sel, const float* __restrict__ ts,
                        const int* __restrict__ cbase,
                        float* __restrict__ out_sc, float* __restrict__ out_idx)
{
    __shared__ int shx[64];
    const int lane = threadIdx.x;   // 64
    const int c = blockIdx.x;
    const int idx = c * 64 + lane;
    const int ex = sel[idx];
    shx[lane] = ex;
    __syncthreads();
    int pre = 0;
#pragma unroll
    for (int j = 0; j < 64; ++j) pre += (int)((j < lane) && (shx[j] == ex));
    const int pos = cbase[c * 64 + ex] + pre;
    out_sc[pos]  = ts[idx];
    out_idx[pos] = (float)(idx >> 1);
}

extern "C" void kernel_launch(void* const* d_in, const int* in_sizes, int n_in,
                              void* d_out, int out_size, void* d_ws, size_t ws_size,
                              hipStream_t stream)
{
    const float* x = (const float*)d_in[0];
    const float* W = (const float*)d_in[1];
    const float* b = (const float*)d_in[2];
    const int* bs_p = (const int*)d_in[3];
    const int* sl_p = (const int*)d_in[4];

    const int E   = in_sizes[2];           // 64
    const int dim = in_sizes[1] / E;       // 2048
    const int N   = in_sizes[0] / dim;     // 16384
    const int total = N * 2;               // slots
    const int nchunks = total / 64;        // 512

    char* ws = (char*)d_ws;
    size_t off = 0;
    int*    hist     = (int*)(ws + off); off += 256;
    double* bsum     = (double*)(ws + off); off += 512;
    int*    nflags   = (int*)(ws + off); off += 256;
    float*  ts       = (float*)(ws + off); off += (size_t)total * 4;
    int*    sel      = (int*)(ws + off); off += (size_t)total * 4;
    int*    flaglist = (int*)(ws + off); off += (size_t)N * 4;
    float*  rzrow    = (float*)(ws + off); off += (size_t)N * 4;
    int*    cnt2     = (int*)(ws + off); off += (size_t)nchunks * 64 * 4;
    int*    cbase    = (int*)(ws + off); off += (size_t)nchunks * 64 * 4;

    // pick largest ksplit whose zpart fits the workspace
    int ksplit = 8;
    while (ksplit > 1 &&
           off + (size_t)ksplit * N * 64 * sizeof(float) > ws_size)
        ksplit >>= 1;
    float* zpart = (float*)(ws + off);

    float* out_sc  = (float*)d_out;
    float* out_idx = out_sc + total;
    float* out_cnt = out_idx + total;
    float* out_rz  = out_cnt + E;

    hipMemsetAsync(ws, 0, 1024, stream);

    const int nrb = N / 128;
    hipLaunchKernelGGL(gemm_kslice, dim3(nrb * ksplit), dim3(256), 0, stream,
                       x, W, dim, N, ksplit, nrb, zpart);
    hipLaunchKernelGGL(epilogue, dim3((N + 3) / 4), dim3(256), 0, stream,
                       zpart, b, N, ksplit, ts, sel, rzrow, nflags, flaglist);
    hipLaunchKernelGGL(fixup, dim3(512), dim3(256), 0, stream,
                       x, W, b, dim, nflags, flaglist, ts, sel);
    hipLaunchKernelGGL(hist_chunks, dim3(nchunks), dim3(64), 0, stream,
                       sel, hist, cnt2);
    hipLaunchKernelGGL(rz_batch, dim3(64), dim3(256), 0, stream,
                       rzrow, bs_p, sl_p, bsum);
    hipLaunchKernelGGL(combine, dim3(1), dim3(64), 0, stream,
                       hist, cnt2, nchunks, cbase, bsum, bs_p, out_cnt, out_rz);
    hipLaunchKernelGGL(scatter, dim3(nchunks), dim3(64), 0, stream,
                       sel, ts, cbase, out_sc, out_idx);
}